// Round 4
// baseline (124.579 us; speedup 1.0000x reference)
//
#include <hip/hip_runtime.h>
#include <math.h>

#define D 512
#define TEMP_INV 14.285714285714286f  // 1/0.07
#define NBT 32                         // 4096 / 128 tile grid dim
#define LROW 72                        // 64 k-elems + 8 pad (bank-group balanced)

typedef __bf16 bf16x8 __attribute__((ext_vector_type(8)));
typedef float f32x4 __attribute__((ext_vector_type(4)));

// ws layout (float units):
//   [0]              neg_sum accumulator
//   [64 .. 64+2048)  p values (positive-pair logits)
//   [4096 .. )       ebf: normalized bf16 matrix [4096][512] (4 MB), 16B aligned

// One wave per row: compute rsqrt(sum sq), scale, RNE-cast to bf16.
__global__ void infonce_norm_cast_kernel(const float* __restrict__ emb,
                                         float* __restrict__ ws, int nrows) {
    if (blockIdx.x == 0 && threadIdx.x == 0) ws[0] = 0.0f;  // zero neg_sum
    unsigned short* __restrict__ ebf = (unsigned short*)(ws + 4096);
    const int lane = threadIdx.x & 63;
    const int wave = threadIdx.x >> 6;
    const int row = blockIdx.x * 4 + wave;
    if (row >= nrows) return;
    const float* r = emb + (size_t)row * D;
    float4 v1 = *(const float4*)&r[lane * 4];
    float4 v2 = *(const float4*)&r[256 + lane * 4];
    float s = v1.x * v1.x + v1.y * v1.y + v1.z * v1.z + v1.w * v1.w
            + v2.x * v2.x + v2.y * v2.y + v2.z * v2.z + v2.w * v2.w;
    #pragma unroll
    for (int off = 32; off > 0; off >>= 1) s += __shfl_down(s, off, 64);
    const float rn = __shfl(rsqrtf(s), 0, 64);

    float f[8] = {v1.x, v1.y, v1.z, v1.w, v2.x, v2.y, v2.z, v2.w};
    unsigned short h[8];
    #pragma unroll
    for (int e = 0; e < 8; ++e) {
        unsigned int u = __float_as_uint(f[e] * rn);
        h[e] = (unsigned short)((u + 0x7FFFu + ((u >> 16) & 1u)) >> 16);  // RNE
    }
    ushort4* dst1 = (ushort4*)&ebf[(size_t)row * D + lane * 4];
    ushort4* dst2 = (ushort4*)&ebf[(size_t)row * D + 256 + lane * 4];
    *dst1 = make_ushort4(h[0], h[1], h[2], h[3]);
    *dst2 = make_ushort4(h[4], h[5], h[6], h[7]);
}

// Upper-triangular 128x128 tiles (528 blocks, 2 blocks/CU by LDS), 256
// threads (4 waves). Wave w -> 64x64 quadrant (wy,wx) as 4x4 MFMA tiles of
// 16x16x32 bf16. BK=64, rotating LDS double-buffer, ONE barrier/iter,
// depth-2 register prefetch (loads for K-chunk it+2 issued at iter it,
// stored to LDS at iter it+1) -> ~2 iters of latency slack.
__global__ __launch_bounds__(256, 2) void infonce_sim_kernel(
        const int* __restrict__ labels, float* __restrict__ ws) {
    // contiguous-per-XCD chunking (528 % 8 == 0)
    const int grp = gridDim.x >> 3;
    const int tile = (blockIdx.x & 7) * grp + (blockIdx.x >> 3);
    // triangular decode: row-major over {(bi,bj): bj>=bi}
    int rem = tile, bi = 0;
    while (rem >= (NBT - bi)) { rem -= (NBT - bi); ++bi; }
    const int bj = bi + rem;

    const unsigned short* __restrict__ ebf = (const unsigned short*)(ws + 4096);
    float* __restrict__ pvals = ws + 64;

    __shared__ unsigned short As[2][128 * LROW];  // 36864 B each pair-half
    __shared__ unsigned short Bs[2][128 * LROW];
    __shared__ int lab_row[128], lab_col[128];
    __shared__ float red[4];

    const int t = threadIdx.x;
    const int w = t >> 6, l = t & 63;
    const int wy = w >> 1, wx = w & 1;
    const int lq = l >> 4, lr = l & 15;  // quad, row-in-tile
    const int rowA0 = bi * 128, rowB0 = bj * 128;

    if (t < 128) lab_row[t] = labels[(rowA0 + t) >> 1];
    else lab_col[t - 128] = labels[(rowB0 + t - 128) >> 1];

    // staging: 1024 x 16B chunks per panel per K-step; thread t does chunks
    // t + s*256, s=0..3 -> rows srow + s*32, col chunk sc.
    const int srow = t >> 3, sc = t & 7;
    const unsigned short* gA0 = ebf + ((size_t)(rowA0 + srow) << 9) + sc * 8;
    const unsigned short* gB0 = ebf + ((size_t)(rowB0 + srow) << 9) + sc * 8;
    const int lofs0 = srow * LROW + sc * 8;
    // s-offsets: global +s*32 rows = s*16384 elems; LDS +s*32*LROW = s*2304

    f32x4 acc[4][4] = {};
    uint4 pA[2][4], pB[2][4];  // two prefetch register sets

    // prologue: K-chunk 0 -> set0 -> buf0; K-chunk 1 -> set1 (left in flight)
    #pragma unroll
    for (int s = 0; s < 4; ++s) {
        pA[0][s] = *(const uint4*)(gA0 + s * 16384);
        pB[0][s] = *(const uint4*)(gB0 + s * 16384);
    }
    #pragma unroll
    for (int s = 0; s < 4; ++s) {
        *(uint4*)&As[0][lofs0 + s * 2304] = pA[0][s];
        *(uint4*)&Bs[0][lofs0 + s * 2304] = pB[0][s];
    }
    #pragma unroll
    for (int s = 0; s < 4; ++s) {
        pA[1][s] = *(const uint4*)(gA0 + s * 16384 + 64);
        pB[1][s] = *(const uint4*)(gB0 + s * 16384 + 64);
    }

    #pragma unroll
    for (int it = 0; it < 8; ++it) {
        const int cur = it & 1;
        __syncthreads();  // publishes buffer `cur`
        if (it < 6) {     // issue K-chunk it+2 into set it&1 (P_it already stored)
            const int k0 = (it + 2) * 64;
            #pragma unroll
            for (int s = 0; s < 4; ++s) {
                pA[it & 1][s] = *(const uint4*)(gA0 + s * 16384 + k0);
                pB[it & 1][s] = *(const uint4*)(gB0 + s * 16384 + k0);
            }
        }
        #pragma unroll
        for (int ks = 0; ks < 2; ++ks) {
            bf16x8 af[4], bfr[4];
            #pragma unroll
            for (int mt = 0; mt < 4; ++mt)
                af[mt] = *(const bf16x8*)&As[cur][(wy * 64 + mt * 16 + lr) * LROW + ks * 32 + lq * 8];
            #pragma unroll
            for (int nt = 0; nt < 4; ++nt)
                bfr[nt] = *(const bf16x8*)&Bs[cur][(wx * 64 + nt * 16 + lr) * LROW + ks * 32 + lq * 8];
            #pragma unroll
            for (int mt = 0; mt < 4; ++mt)
                #pragma unroll
                for (int nt = 0; nt < 4; ++nt)
                    acc[mt][nt] = __builtin_amdgcn_mfma_f32_16x16x32_bf16(
                        af[mt], bfr[nt], acc[mt][nt], 0, 0, 0);
        }
        if (it < 7) {  // store K-chunk it+1 (set (it+1)&1) into the other buffer
            const int nxt = cur ^ 1;
            #pragma unroll
            for (int s = 0; s < 4; ++s) {
                *(uint4*)&As[nxt][lofs0 + s * 2304] = pA[(it + 1) & 1][s];
                *(uint4*)&Bs[nxt][lofs0 + s * 2304] = pB[(it + 1) & 1][s];
            }
        }
    }

    // Epilogue: C/D layout per 16x16 tile: row = lq*4+r, col = lr.
    float neg_local = 0.0f;
    #pragma unroll
    for (int mt = 0; mt < 4; ++mt) {
        #pragma unroll
        for (int nt = 0; nt < 4; ++nt) {
            const f32x4 a = acc[mt][nt];
            #pragma unroll
            for (int r = 0; r < 4; ++r) {
                const int li = wy * 64 + mt * 16 + lq * 4 + r;
                const int lj = wx * 64 + nt * 16 + lr;
                const int i = rowA0 + li;
                const int j = rowB0 + lj;
                const float S = a[r] * TEMP_INV;
                if (j > i) {
                    if (lab_row[li] != lab_col[lj]) neg_local += __expf(S);
                    if (!(i & 1) && j == i + 1) pvals[i >> 1] = S;
                }
            }
        }
    }

    float s = neg_local;
    #pragma unroll
    for (int off = 32; off > 0; off >>= 1) s += __shfl_down(s, off, 64);
    if (l == 0) red[w] = s;
    __syncthreads();
    if (t == 0) atomicAdd(ws, red[0] + red[1] + red[2] + red[3]);
}

__global__ void infonce_loss_kernel(const float* __restrict__ ws,
                                    float* __restrict__ out, int npairs) {
    __shared__ float red[4];
    const float neg = ws[0];
    const float* __restrict__ p = ws + 64;
    float local = 0.0f;
    for (int k = threadIdx.x; k < npairs; k += 256) {
        const float pv = p[k];
        local += logf(__expf(pv) + neg) - pv;
    }
    float s = local;
    #pragma unroll
    for (int off = 32; off > 0; off >>= 1) s += __shfl_down(s, off, 64);
    if ((threadIdx.x & 63) == 0) red[threadIdx.x >> 6] = s;
    __syncthreads();
    if (threadIdx.x == 0)
        out[0] = (red[0] + red[1] + red[2] + red[3]) / (float)npairs;
}

extern "C" void kernel_launch(void* const* d_in, const int* in_sizes, int n_in,
                              void* d_out, int out_size, void* d_ws, size_t ws_size,
                              hipStream_t stream) {
    const float* emb = (const float*)d_in[0];
    const int* labels = (const int*)d_in[1];
    float* out = (float*)d_out;
    float* ws = (float*)d_ws;

    const int ntot = in_sizes[0] / D;  // 4096
    const int npairs = ntot / 2;       // 2048 positive pairs

    infonce_norm_cast_kernel<<<ntot / 4, 256, 0, stream>>>(emb, ws, ntot);
    const int nbt = ntot / 128;
    const int nblk = nbt * (nbt + 1) / 2;  // 528 upper-tri tiles
    infonce_sim_kernel<<<nblk, 256, 0, stream>>>(labels, ws);
    infonce_loss_kernel<<<1, 256, 0, stream>>>(ws, out, npairs);
}